// Round 2
// baseline (4498.189 us; speedup 1.0000x reference)
//
#include <hip/hip_runtime.h>
#include <hip/hip_bf16.h>
#include <stdint.h>

typedef __hip_bfloat16 bf16;
typedef float f32x4 __attribute__((ext_vector_type(4)));
typedef __bf16 bf16x8 __attribute__((ext_vector_type(8)));

__device__ __forceinline__ float b2f(bf16 v) { return __bfloat162float(v); }
__device__ __forceinline__ bf16 f2b(float v) { return __float2bfloat16(v); }
// bit-level RNE f32->bf16 (finite inputs), independent of hip_bf16 ABI drift
__device__ __forceinline__ unsigned short f2bu(float f) {
  unsigned u = __float_as_uint(f);
  unsigned r = u + 0x7fffu + ((u >> 16) & 1u);
  return (unsigned short)(r >> 16);
}

// B=4, N=4096, D_POINTS=512, D_MODEL=256, K=16
// rows (b,n): 16384 ; rows (b,n,j): 262144

// ---------------- weight transpose + f32->bf16 (tiny, once per launch) ----------------
__global__ __launch_bounds__(256) void transpose_k(const float* __restrict__ src,
                                                   bf16* __restrict__ dst,
                                                   int R, int C) {
  int i = blockIdx.x * 256 + threadIdx.x;
  if (i < R * C) {
    int r = i / C, c = i - r * C;
    dst[c * R + r] = f2b(src[i]);
  }
}

// ---------------- KNN: stable top-16 per query (exact f32, np op order) ----------------
__global__ __launch_bounds__(256) void knn_kernel(const float* __restrict__ xyz,
                                                  int* __restrict__ gidx) {
  __shared__ __align__(16) char ldsbuf[65536];
  float4* pts = reinterpret_cast<float4*>(ldsbuf);
  unsigned long long* keys = reinterpret_cast<unsigned long long*>(ldsbuf);

  int tid = threadIdx.x;
  int qblock = blockIdx.x * 64;
  int batch = qblock >> 12;
  const float* xb = xyz + (size_t)batch * 4096 * 3;

  for (int i = tid; i < 4096; i += 256) {
    float x = xb[i * 3 + 0];
    float y = xb[i * 3 + 1];
    float z = xb[i * 3 + 2];
    float sq = __fadd_rn(__fadd_rn(__fmul_rn(x, x), __fmul_rn(y, y)), __fmul_rn(z, z));
    pts[i] = make_float4(x, y, z, sq);
  }
  __syncthreads();

  int lq = tid & 63;
  int sub = tid >> 6;
  int nloc = (qblock & 4095) + lq;
  float4 Q = pts[nloc];

  float dist[16];
  int idx[16];
#pragma unroll
  for (int i = 0; i < 16; ++i) { dist[i] = 3.4e38f; idx[i] = 0; }

  int mstart = sub * 1024;
  for (int t = 0; t < 1024; ++t) {
    int m = mstart + t;
    float4 P = pts[m];
    float dot = __fadd_rn(__fadd_rn(__fmul_rn(Q.x, P.x), __fmul_rn(Q.y, P.y)),
                          __fmul_rn(Q.z, P.z));
    float d = __fsub_rn(__fadd_rn(Q.w, P.w), __fmul_rn(2.0f, dot));
    if (d < dist[15]) {               // strict < : lower index wins ties (top_k stable)
      dist[15] = d; idx[15] = m;
#pragma unroll
      for (int s = 15; s > 0; --s) {
        bool sw = dist[s] < dist[s - 1];
        float lo = sw ? dist[s] : dist[s - 1];
        float hi = sw ? dist[s - 1] : dist[s];
        int loi = sw ? idx[s] : idx[s - 1];
        int hii = sw ? idx[s - 1] : idx[s];
        dist[s - 1] = lo; dist[s] = hi; idx[s - 1] = loi; idx[s] = hii;
      }
    }
  }

  __syncthreads();  // done with pts; reuse LDS for merge keys
#pragma unroll
  for (int i = 0; i < 16; ++i) {
    unsigned u = __float_as_uint(dist[i]);
    u ^= (unsigned)((int)u >> 31) | 0x80000000u;   // monotonic float bits
    keys[(lq * 4 + sub) * 16 + i] = ((unsigned long long)u << 32) | (unsigned)idx[i];
  }
  __syncthreads();

  if (tid < 64) {  // 4-way merge of sorted 16-lists -> final 16
    const unsigned long long* L = keys + tid * 64;
    int h0 = 0, h1 = 0, h2 = 0, h3 = 0;
    int qg = qblock + tid;
    int base = batch * 4096;
    for (int j = 0; j < 16; ++j) {
      unsigned long long k0 = (h0 < 16) ? L[h0] : ~0ull;
      unsigned long long k1 = (h1 < 16) ? L[16 + h1] : ~0ull;
      unsigned long long k2 = (h2 < 16) ? L[32 + h2] : ~0ull;
      unsigned long long k3 = (h3 < 16) ? L[48 + h3] : ~0ull;
      unsigned long long m01 = k0 < k1 ? k0 : k1;
      unsigned long long m23 = k2 < k3 ? k2 : k3;
      unsigned long long mn = m01 < m23 ? m01 : m23;
      gidx[(size_t)qg * 16 + j] = base + (int)(mn & 0xffffffffu);
      if (mn == k0) h0++;
      else if (mn == k1) h1++;
      else if (mn == k2) h2++;
      else h3++;
    }
  }
}

// ---------------- hidden = relu(rel @ Wd1 + bd1)  [262144,256] bf16 out ----------------
__global__ __launch_bounds__(256) void hidden_kernel(const float* __restrict__ xyz,
                                                     const int* __restrict__ gidx,
                                                     const float* __restrict__ Wd1,
                                                     const float* __restrict__ bd1,
                                                     bf16* __restrict__ hidden) {
  __shared__ float rel[16][3];
  int q = blockIdx.x;
  int tid = threadIdx.x;
  if (tid < 16) {
    int g = gidx[q * 16 + tid];
    rel[tid][0] = xyz[(size_t)q * 3 + 0] - xyz[(size_t)g * 3 + 0];
    rel[tid][1] = xyz[(size_t)q * 3 + 1] - xyz[(size_t)g * 3 + 1];
    rel[tid][2] = xyz[(size_t)q * 3 + 2] - xyz[(size_t)g * 3 + 2];
  }
  __syncthreads();
  float w0 = Wd1[tid], w1 = Wd1[256 + tid], w2 = Wd1[512 + tid];
  float bb = bd1[tid];
#pragma unroll
  for (int j = 0; j < 16; ++j) {
    float v = rel[j][0] * w0 + rel[j][1] * w1 + rel[j][2] * w2 + bb;
    v = fmaxf(v, 0.0f);
    hidden[((size_t)q * 16 + j) * 256 + tid] = f2b(v);
  }
}

// ---------------- tiled bf16 MFMA GEMM: C = A[M,K] @ BT[N,K]^T ----------------
// 128x128 tile per block; 4 waves, each 64x64 via 4x4 mfma_f32_16x16x32_bf16.
// AT: float (converted during staging) or bf16. CT: float or bf16.
// EPI: 0 +bias ; 1 relu(+bias) ; 2 h/vp gather epilogue ; 3 softmax/attn/res_pre ;
//      4 +bias+resid(f32)
template <int EPI, typename AT, typename CT>
__global__ __launch_bounds__(256) void gemm_bt(
    const AT* __restrict__ A, const bf16* __restrict__ BT,
    const float* __restrict__ bias, CT* __restrict__ C,
    int M, int N, int K,
    const bf16* __restrict__ e0p, const bf16* __restrict__ e1p,
    const bf16* __restrict__ e2p, const int* __restrict__ gidx,
    bf16* __restrict__ o1, const float* __restrict__ resid) {
  __shared__ __align__(16) unsigned short As[128 * 72];
  __shared__ __align__(16) unsigned short Bs[128 * 72];

  int ntn = N >> 7;
  int bx = blockIdx.x % ntn, by = blockIdx.x / ntn;
  int m0 = by * 128, n0 = bx * 128;
  int tid = threadIdx.x;
  int wave = tid >> 6, lane = tid & 63;
  int wr = wave >> 1, wc = wave & 1;
  int lm = lane & 15, lqd = lane >> 4;

  f32x4 acc[4][4] = {};

  for (int k0 = 0; k0 < K; k0 += 64) {
#pragma unroll
    for (int i = 0; i < 4; ++i) {
      int flat = i * 256 + tid;
      int row = flat >> 3;
      int u = flat & 7;
      if constexpr (sizeof(AT) == 4) {
        const float* ap = (const float*)A + (size_t)(m0 + row) * K + k0 + u * 8;
        float4 a0 = *reinterpret_cast<const float4*>(ap);
        float4 a1 = *reinterpret_cast<const float4*>(ap + 4);
        unsigned short* dst = &As[row * 72 + u * 8];
        dst[0] = f2bu(a0.x); dst[1] = f2bu(a0.y); dst[2] = f2bu(a0.z); dst[3] = f2bu(a0.w);
        dst[4] = f2bu(a1.x); dst[5] = f2bu(a1.y); dst[6] = f2bu(a1.z); dst[7] = f2bu(a1.w);
      } else {
        int4 av = *reinterpret_cast<const int4*>((const bf16*)A + (size_t)(m0 + row) * K + k0 + u * 8);
        *reinterpret_cast<int4*>(&As[row * 72 + u * 8]) = av;
      }
      int4 bv = *reinterpret_cast<const int4*>(BT + (size_t)(n0 + row) * K + k0 + u * 8);
      *reinterpret_cast<int4*>(&Bs[row * 72 + u * 8]) = bv;
    }
    __syncthreads();
#pragma unroll
    for (int ks = 0; ks < 2; ++ks) {
      bf16x8 af[4], bfr[4];
#pragma unroll
      for (int mi = 0; mi < 4; ++mi)
        af[mi] = *reinterpret_cast<const bf16x8*>(
            &As[(wr * 64 + mi * 16 + lm) * 72 + ks * 32 + lqd * 8]);
#pragma unroll
      for (int ni = 0; ni < 4; ++ni)
        bfr[ni] = *reinterpret_cast<const bf16x8*>(
            &Bs[(wc * 64 + ni * 16 + lm) * 72 + ks * 32 + lqd * 8]);
#pragma unroll
      for (int mi = 0; mi < 4; ++mi)
#pragma unroll
        for (int ni = 0; ni < 4; ++ni)
          acc[mi][ni] = __builtin_amdgcn_mfma_f32_16x16x32_bf16(af[mi], bfr[ni],
                                                                acc[mi][ni], 0, 0, 0);
    }
    __syncthreads();
  }

#pragma unroll
  for (int mi = 0; mi < 4; ++mi) {
    int mbase = m0 + wr * 64 + mi * 16;
#pragma unroll
    for (int ni = 0; ni < 4; ++ni) {
      int n = n0 + wc * 64 + ni * 16 + lm;
      float bv = bias ? bias[n] : 0.0f;
      if constexpr (EPI == 3) {
        // softmax over the 16 rows (neighbors of one (b,n)) per column
        float l0 = acc[mi][ni][0] + bv, l1 = acc[mi][ni][1] + bv;
        float l2 = acc[mi][ni][2] + bv, l3 = acc[mi][ni][3] + bv;
        float mx = fmaxf(fmaxf(l0, l1), fmaxf(l2, l3));
        mx = fmaxf(mx, __shfl_xor(mx, 16, 64));
        mx = fmaxf(mx, __shfl_xor(mx, 32, 64));
        float ev[4];
        ev[0] = __expf((l0 - mx) * 0.0625f);
        ev[1] = __expf((l1 - mx) * 0.0625f);
        ev[2] = __expf((l2 - mx) * 0.0625f);
        ev[3] = __expf((l3 - mx) * 0.0625f);
        float s = ev[0] + ev[1] + ev[2] + ev[3];
        s += __shfl_xor(s, 16, 64);
        s += __shfl_xor(s, 32, 64);
        float inv = 1.0f / s;
        float rp = 0.0f;
#pragma unroll
        for (int r = 0; r < 4; ++r) {
          size_t m = (size_t)(mbase + lqd * 4 + r);
          float a = ev[r] * inv;
          C[m * 256 + n] = a;                            // attn (f32 out)
          rp += a * b2f(e2p[m * 256 + n]);               // * (v + pos_enc)
        }
        rp += __shfl_xor(rp, 16, 64);
        rp += __shfl_xor(rp, 32, 64);
        if (lqd == 0) o1[(size_t)(mbase >> 4) * 256 + n] = f2b(rp);  // res_pre (bf16)
      } else {
#pragma unroll
        for (int r = 0; r < 4; ++r) {
          size_t m = (size_t)(mbase + lqd * 4 + r);
          float v = acc[mi][ni][r] + bv;
          if constexpr (EPI == 1) v = fmaxf(v, 0.0f);
          if constexpr (EPI == 2) {
            int g = gidx[m];
            float qv = b2f(e0p[(m >> 4) * (size_t)256 + n]);
            float kv = b2f(e1p[(size_t)g * 256 + n]);
            float vv = b2f(e2p[(size_t)g * 256 + n]);
            C[m * (size_t)N + n] = f2b(qv - kv + v);     // h
            o1[m * (size_t)N + n] = f2b(vv + v);         // vp
          } else if constexpr (EPI == 4) {
            v += resid[m * (size_t)N + n];
            C[m * (size_t)N + n] = v;                    // res (f32 out)
          } else {
            C[m * (size_t)N + n] = f2b(v);
          }
        }
      }
    }
  }
}

// ---------------- launcher ----------------
extern "C" void kernel_launch(void* const* d_in, const int* in_sizes, int n_in,
                              void* d_out, int out_size, void* d_ws, size_t ws_size,
                              hipStream_t stream) {
  const float* xyz = (const float*)d_in[0];
  const float* feat = (const float*)d_in[1];
  const float* W1 = (const float*)d_in[2];
  const float* b1 = (const float*)d_in[3];
  const float* W2 = (const float*)d_in[4];
  const float* b2 = (const float*)d_in[5];
  const float* Wd1 = (const float*)d_in[6];
  const float* bd1 = (const float*)d_in[7];
  const float* Wd2 = (const float*)d_in[8];
  const float* bd2 = (const float*)d_in[9];
  const float* Wg1 = (const float*)d_in[10];
  const float* bg1 = (const float*)d_in[11];
  const float* Wg2 = (const float*)d_in[12];
  const float* bg2 = (const float*)d_in[13];
  const float* Wq = (const float*)d_in[14];
  const float* Wk = (const float*)d_in[15];
  const float* Wv = (const float*)d_in[16];

  // workspace layout (bytes)
  constexpr size_t XBUF = 0;                   // [16384,256] bf16
  constexpr size_t QBUF = 8388608;
  constexpr size_t KBUF = 16777216;
  constexpr size_t VBUF = 25165824;
  constexpr size_t RESPRE = 33554432;          // [16384,256] bf16
  constexpr size_t GIDX = 41943040;            // [262144] int
  constexpr size_t W1T = 42991616;             // [256,512] bf16
  constexpr size_t W2T = 43253760;             // [512,256] bf16
  constexpr size_t WQT = 43515904;
  constexpr size_t WKT = 43646976;
  constexpr size_t WVT = 43778048;
  constexpr size_t WD2T = 43909120;
  constexpr size_t WG1T = 44040192;
  constexpr size_t WG2T = 44171264;
  constexpr size_t HIDDEN = 44302336;          // [262144,256] bf16 (reused as g)
  constexpr size_t HBUF = 178520064;           // [262144,256] bf16
  constexpr size_t VPBUF = 312737792;          // [262144,256] bf16
  constexpr size_t WS_NEEDED = 446955520;
  if (ws_size < WS_NEEDED) return;

  char* ws = (char*)d_ws;
  bf16* xbuf = (bf16*)(ws + XBUF);
  bf16* qbuf = (bf16*)(ws + QBUF);
  bf16* kbuf = (bf16*)(ws + KBUF);
  bf16* vbuf = (bf16*)(ws + VBUF);
  bf16* respre = (bf16*)(ws + RESPRE);
  int* gidx = (int*)(ws + GIDX);
  bf16* w1t = (bf16*)(ws + W1T);
  bf16* w2t = (bf16*)(ws + W2T);
  bf16* wqt = (bf16*)(ws + WQT);
  bf16* wkt = (bf16*)(ws + WKT);
  bf16* wvt = (bf16*)(ws + WVT);
  bf16* wd2t = (bf16*)(ws + WD2T);
  bf16* wg1t = (bf16*)(ws + WG1T);
  bf16* wg2t = (bf16*)(ws + WG2T);
  bf16* hidden = (bf16*)(ws + HIDDEN);
  bf16* hbuf = (bf16*)(ws + HBUF);
  bf16* vpbuf = (bf16*)(ws + VPBUF);

  float* res_out = (float*)d_out;
  float* attn_out = res_out + (size_t)16384 * 512;

  transpose_k<<<512, 256, 0, stream>>>(W1, w1t, 512, 256);
  transpose_k<<<512, 256, 0, stream>>>(W2, w2t, 256, 512);
  transpose_k<<<256, 256, 0, stream>>>(Wq, wqt, 256, 256);
  transpose_k<<<256, 256, 0, stream>>>(Wk, wkt, 256, 256);
  transpose_k<<<256, 256, 0, stream>>>(Wv, wvt, 256, 256);
  transpose_k<<<256, 256, 0, stream>>>(Wd2, wd2t, 256, 256);
  transpose_k<<<256, 256, 0, stream>>>(Wg1, wg1t, 256, 256);
  transpose_k<<<256, 256, 0, stream>>>(Wg2, wg2t, 256, 256);

  knn_kernel<<<256, 256, 0, stream>>>(xyz, gidx);

  // x = feat @ W1 + b1   (f32 A staged->bf16)
  gemm_bt<0, float, bf16><<<128 * 2, 256, 0, stream>>>(
      feat, w1t, b1, xbuf, 16384, 256, 512,
      nullptr, nullptr, nullptr, nullptr, nullptr, nullptr);
  // q/k/v = x @ W{q,k,v}
  gemm_bt<0, bf16, bf16><<<128 * 2, 256, 0, stream>>>(
      xbuf, wqt, nullptr, qbuf, 16384, 256, 256,
      nullptr, nullptr, nullptr, nullptr, nullptr, nullptr);
  gemm_bt<0, bf16, bf16><<<128 * 2, 256, 0, stream>>>(
      xbuf, wkt, nullptr, kbuf, 16384, 256, 256,
      nullptr, nullptr, nullptr, nullptr, nullptr, nullptr);
  gemm_bt<0, bf16, bf16><<<128 * 2, 256, 0, stream>>>(
      xbuf, wvt, nullptr, vbuf, 16384, 256, 256,
      nullptr, nullptr, nullptr, nullptr, nullptr, nullptr);

  hidden_kernel<<<16384, 256, 0, stream>>>(xyz, gidx, Wd1, bd1, hidden);

  // pos_enc = hidden @ Wd2 + bd2 ; h = q - k_g + pos ; vp = v_g + pos
  gemm_bt<2, bf16, bf16><<<2048 * 2, 256, 0, stream>>>(
      hidden, wd2t, bd2, hbuf, 262144, 256, 256,
      qbuf, kbuf, vbuf, gidx, vpbuf, nullptr);
  // g = relu(h @ Wg1 + bg1)  (into hidden, already consumed)
  gemm_bt<1, bf16, bf16><<<2048 * 2, 256, 0, stream>>>(
      hbuf, wg1t, bg1, hidden, 262144, 256, 256,
      nullptr, nullptr, nullptr, nullptr, nullptr, nullptr);
  // logits = g @ Wg2 + bg2 ; softmax over 16 ; attn (f32) + res_pre (bf16)
  gemm_bt<3, bf16, float><<<2048 * 2, 256, 0, stream>>>(
      hidden, wg2t, bg2, attn_out, 262144, 256, 256,
      nullptr, nullptr, vpbuf, nullptr, respre, nullptr);
  // res = res_pre @ W2 + b2 + features  (f32 out)
  gemm_bt<4, bf16, float><<<128 * 4, 256, 0, stream>>>(
      respre, w2t, b2, res_out, 16384, 512, 256,
      nullptr, nullptr, nullptr, nullptr, nullptr, feat);
}

// Round 3
// 1165.426 us; speedup vs baseline: 3.8597x; 3.8597x over previous
//
#include <hip/hip_runtime.h>
#include <hip/hip_bf16.h>
#include <stdint.h>

typedef __hip_bfloat16 bf16;
typedef float f32x4 __attribute__((ext_vector_type(4)));
typedef __bf16 bf16x8 __attribute__((ext_vector_type(8)));

__device__ __forceinline__ float b2f(bf16 v) { return __bfloat162float(v); }
__device__ __forceinline__ bf16 f2b(float v) { return __float2bfloat16(v); }
__device__ __forceinline__ unsigned short f2bu(float f) {
  unsigned u = __float_as_uint(f);
  unsigned r = u + 0x7fffu + ((u >> 16) & 1u);
  return (unsigned short)(r >> 16);
}

// B=4, N=4096, D_POINTS=512, D_MODEL=256, K=16

// compare-exchange on u64 keys: min -> a, max -> b (1 cmp + 4 cndmask, no arrays)
#define CE64(a, b)                                            \
  do {                                                        \
    bool c_ = (b) < (a);                                      \
    unsigned long long lo_ = c_ ? (b) : (a);                  \
    unsigned long long hi_ = c_ ? (a) : (b);                  \
    (a) = lo_; (b) = hi_;                                     \
  } while (0)

// ---------------- pack xyz -> float4(x,y,z,sq) ----------------
__global__ __launch_bounds__(256) void pack_pts(const float* __restrict__ xyz,
                                                float4* __restrict__ pts) {
  int i = blockIdx.x * 256 + threadIdx.x;   // 0..16383
  float x = xyz[i * 3 + 0];
  float y = xyz[i * 3 + 1];
  float z = xyz[i * 3 + 2];
  float sq = __fadd_rn(__fadd_rn(__fmul_rn(x, x), __fmul_rn(y, y)), __fmul_rn(z, z));
  pts[i] = make_float4(x, y, z, sq);
}

// ---------------- knn partial: 1024 blocks; block=(group g, range r) ----------------
// wave w scans candidates [r*1024+w*256, +256) for 64 queries (lane=query).
// Output: 16 sorted u64 lists per query, layout keys[(rw*16+j)*16384 + q].
__global__ __launch_bounds__(256) void knn_partial(const float4* __restrict__ pts,
                                                   unsigned long long* __restrict__ keys) {
  __shared__ __align__(16) float4 cs[1024];
  __shared__ __align__(16) float4 qs[64];

  int tid = threadIdx.x;
  int g = blockIdx.x >> 2;          // query group 0..255 (64 queries each)
  int r = blockIdx.x & 3;           // candidate range
  int batch = g >> 6;
  const float4* pp = pts + batch * 4096;
  int cb = r * 1024;

#pragma unroll
  for (int i = 0; i < 4; ++i) cs[i * 256 + tid] = pp[cb + i * 256 + tid];
  if (tid < 64) qs[tid] = pp[(g & 63) * 64 + tid];
  __syncthreads();

  int wave = tid >> 6, lq = tid & 63;
  float4 Q = qs[lq];
  int mbase = cb + wave * 256;

  unsigned long long k0 = ~0ull, k1 = ~0ull, k2 = ~0ull, k3 = ~0ull;
  unsigned long long k4 = ~0ull, k5 = ~0ull, k6 = ~0ull, k7 = ~0ull;
  unsigned long long k8 = ~0ull, k9 = ~0ull, k10 = ~0ull, k11 = ~0ull;
  unsigned long long k12 = ~0ull, k13 = ~0ull, k14 = ~0ull, k15 = ~0ull;

  for (int t = 0; t < 256; ++t) {
    float4 P = cs[wave * 256 + t];
    float dot = __fadd_rn(__fadd_rn(__fmul_rn(Q.x, P.x), __fmul_rn(Q.y, P.y)),
                          __fmul_rn(Q.z, P.z));
    float d = __fsub_rn(__fadd_rn(Q.w, P.w), __fmul_rn(2.0f, dot));
    unsigned u = __float_as_uint(d);
    u ^= (unsigned)((int)u >> 31) | 0x80000000u;   // monotonic float bits
    unsigned long long nk = ((unsigned long long)u << 32) | (unsigned)(mbase + t);
    if (nk < k15) {
      k15 = nk;
      CE64(k14, k15); CE64(k13, k14); CE64(k12, k13); CE64(k11, k12);
      CE64(k10, k11); CE64(k9, k10);  CE64(k8, k9);   CE64(k7, k8);
      CE64(k6, k7);   CE64(k5, k6);   CE64(k4, k5);   CE64(k3, k4);
      CE64(k2, k3);   CE64(k1, k2);   CE64(k0, k1);
    }
  }

  int rw = r * 4 + wave;
  int q = g * 64 + lq;
  unsigned long long* o = keys + (size_t)(rw * 16) * 16384 + q;
  o[0] = k0;           o[16384] = k1;       o[2 * 16384] = k2;   o[3 * 16384] = k3;
  o[4 * 16384] = k4;   o[5 * 16384] = k5;   o[6 * 16384] = k6;   o[7 * 16384] = k7;
  o[8 * 16384] = k8;   o[9 * 16384] = k9;   o[10 * 16384] = k10; o[11 * 16384] = k11;
  o[12 * 16384] = k12; o[13 * 16384] = k13; o[14 * 16384] = k14; o[15 * 16384] = k15;
}

// ---------------- knn merge: 16 sorted lists -> final 16, thread per query ----------------
__global__ __launch_bounds__(256) void knn_merge(const unsigned long long* __restrict__ keys,
                                                 int* __restrict__ gidx) {
  int q = blockIdx.x * 256 + threadIdx.x;   // 0..16383
  const unsigned long long* kq = keys + q;

#define LOADL(rw)                                   \
  unsigned long long l0 = kq[((rw) * 16 + 0) * 16384],  l1 = kq[((rw) * 16 + 1) * 16384],  \
                     l2 = kq[((rw) * 16 + 2) * 16384],  l3 = kq[((rw) * 16 + 3) * 16384],  \
                     l4 = kq[((rw) * 16 + 4) * 16384],  l5 = kq[((rw) * 16 + 5) * 16384],  \
                     l6 = kq[((rw) * 16 + 6) * 16384],  l7 = kq[((rw) * 16 + 7) * 16384],  \
                     l8 = kq[((rw) * 16 + 8) * 16384],  l9 = kq[((rw) * 16 + 9) * 16384],  \
                     l10 = kq[((rw) * 16 + 10) * 16384], l11 = kq[((rw) * 16 + 11) * 16384], \
                     l12 = kq[((rw) * 16 + 12) * 16384], l13 = kq[((rw) * 16 + 13) * 16384], \
                     l14 = kq[((rw) * 16 + 14) * 16384], l15 = kq[((rw) * 16 + 15) * 16384]

  unsigned long long a0 = kq[0],           a1 = kq[16384],      a2 = kq[2 * 16384],
                     a3 = kq[3 * 16384],   a4 = kq[4 * 16384],  a5 = kq[5 * 16384],
                     a6 = kq[6 * 16384],   a7 = kq[7 * 16384],  a8 = kq[8 * 16384],
                     a9 = kq[9 * 16384],   a10 = kq[10 * 16384], a11 = kq[11 * 16384],
                     a12 = kq[12 * 16384], a13 = kq[13 * 16384], a14 = kq[14 * 16384],
                     a15 = kq[15 * 16384];

  for (int rw = 1; rw < 16; ++rw) {
    LOADL(rw);
    // lower half of bitonic merge of (a asc ++ l desc): min(a_i, l_{15-i}) -> bitonic
    a0 = a0 < l15 ? a0 : l15;   a1 = a1 < l14 ? a1 : l14;
    a2 = a2 < l13 ? a2 : l13;   a3 = a3 < l12 ? a3 : l12;
    a4 = a4 < l11 ? a4 : l11;   a5 = a5 < l10 ? a5 : l10;
    a6 = a6 < l9 ? a6 : l9;     a7 = a7 < l8 ? a7 : l8;
    a8 = a8 < l7 ? a8 : l7;     a9 = a9 < l6 ? a9 : l6;
    a10 = a10 < l5 ? a10 : l5;  a11 = a11 < l4 ? a11 : l4;
    a12 = a12 < l3 ? a12 : l3;  a13 = a13 < l2 ? a13 : l2;
    a14 = a14 < l1 ? a14 : l1;  a15 = a15 < l0 ? a15 : l0;
    // bitonic sort of 16 bitonic elements: stages 8,4,2,1
    CE64(a0, a8);  CE64(a1, a9);  CE64(a2, a10); CE64(a3, a11);
    CE64(a4, a12); CE64(a5, a13); CE64(a6, a14); CE64(a7, a15);
    CE64(a0, a4);  CE64(a1, a5);  CE64(a2, a6);  CE64(a3, a7);
    CE64(a8, a12); CE64(a9, a13); CE64(a10, a14); CE64(a11, a15);
    CE64(a0, a2);  CE64(a1, a3);  CE64(a4, a6);  CE64(a5, a7);
    CE64(a8, a10); CE64(a9, a11); CE64(a12, a14); CE64(a13, a15);
    CE64(a0, a1);  CE64(a2, a3);  CE64(a4, a5);  CE64(a6, a7);
    CE64(a8, a9);  CE64(a10, a11); CE64(a12, a13); CE64(a14, a15);
  }
#undef LOADL

  int base = (q >> 12) << 12;   // batch*4096
  int* o = gidx + (size_t)q * 16;
  o[0] = base + (int)(a0 & 0xffffffffu);   o[1] = base + (int)(a1 & 0xffffffffu);
  o[2] = base + (int)(a2 & 0xffffffffu);   o[3] = base + (int)(a3 & 0xffffffffu);
  o[4] = base + (int)(a4 & 0xffffffffu);   o[5] = base + (int)(a5 & 0xffffffffu);
  o[6] = base + (int)(a6 & 0xffffffffu);   o[7] = base + (int)(a7 & 0xffffffffu);
  o[8] = base + (int)(a8 & 0xffffffffu);   o[9] = base + (int)(a9 & 0xffffffffu);
  o[10] = base + (int)(a10 & 0xffffffffu); o[11] = base + (int)(a11 & 0xffffffffu);
  o[12] = base + (int)(a12 & 0xffffffffu); o[13] = base + (int)(a13 & 0xffffffffu);
  o[14] = base + (int)(a14 & 0xffffffffu); o[15] = base + (int)(a15 & 0xffffffffu);
}

// ---------------- weight transpose + f32->bf16 ----------------
__global__ __launch_bounds__(256) void transpose_k(const float* __restrict__ src,
                                                   bf16* __restrict__ dst,
                                                   int R, int C) {
  int i = blockIdx.x * 256 + threadIdx.x;
  if (i < R * C) {
    int r = i / C, c = i - r * C;
    dst[c * R + r] = f2b(src[i]);
  }
}

// ---------------- hidden = relu(rel @ Wd1 + bd1) ----------------
__global__ __launch_bounds__(256) void hidden_kernel(const float* __restrict__ xyz,
                                                     const int* __restrict__ gidx,
                                                     const float* __restrict__ Wd1,
                                                     const float* __restrict__ bd1,
                                                     bf16* __restrict__ hidden) {
  __shared__ float rel[16][3];
  int q = blockIdx.x;
  int tid = threadIdx.x;
  if (tid < 16) {
    int g = gidx[q * 16 + tid];
    rel[tid][0] = xyz[(size_t)q * 3 + 0] - xyz[(size_t)g * 3 + 0];
    rel[tid][1] = xyz[(size_t)q * 3 + 1] - xyz[(size_t)g * 3 + 1];
    rel[tid][2] = xyz[(size_t)q * 3 + 2] - xyz[(size_t)g * 3 + 2];
  }
  __syncthreads();
  float w0 = Wd1[tid], w1 = Wd1[256 + tid], w2 = Wd1[512 + tid];
  float bb = bd1[tid];
#pragma unroll
  for (int j = 0; j < 16; ++j) {
    float v = rel[j][0] * w0 + rel[j][1] * w1 + rel[j][2] * w2 + bb;
    v = fmaxf(v, 0.0f);
    hidden[((size_t)q * 16 + j) * 256 + tid] = f2b(v);
  }
}

// ---------------- tiled bf16 MFMA GEMM: C = A[M,K] @ BT[N,K]^T ----------------
template <int EPI, typename AT, typename CT>
__global__ __launch_bounds__(256) void gemm_bt(
    const AT* __restrict__ A, const bf16* __restrict__ BT,
    const float* __restrict__ bias, CT* __restrict__ C,
    int M, int N, int K,
    const bf16* __restrict__ e0p, const bf16* __restrict__ e1p,
    const bf16* __restrict__ e2p, const int* __restrict__ gidx,
    bf16* __restrict__ o1, const float* __restrict__ resid) {
  __shared__ __align__(16) unsigned short As[128 * 72];
  __shared__ __align__(16) unsigned short Bs[128 * 72];

  int ntn = N >> 7;
  int bx = blockIdx.x % ntn, by = blockIdx.x / ntn;
  int m0 = by * 128, n0 = bx * 128;
  int tid = threadIdx.x;
  int wave = tid >> 6, lane = tid & 63;
  int wr = wave >> 1, wc = wave & 1;
  int lm = lane & 15, lqd = lane >> 4;

  f32x4 acc[4][4] = {};

  for (int k0 = 0; k0 < K; k0 += 64) {
#pragma unroll
    for (int i = 0; i < 4; ++i) {
      int flat = i * 256 + tid;
      int row = flat >> 3;
      int u = flat & 7;
      if constexpr (sizeof(AT) == 4) {
        const float* ap = (const float*)A + (size_t)(m0 + row) * K + k0 + u * 8;
        float4 a0 = *reinterpret_cast<const float4*>(ap);
        float4 a1 = *reinterpret_cast<const float4*>(ap + 4);
        unsigned short* dst = &As[row * 72 + u * 8];
        dst[0] = f2bu(a0.x); dst[1] = f2bu(a0.y); dst[2] = f2bu(a0.z); dst[3] = f2bu(a0.w);
        dst[4] = f2bu(a1.x); dst[5] = f2bu(a1.y); dst[6] = f2bu(a1.z); dst[7] = f2bu(a1.w);
      } else {
        int4 av = *reinterpret_cast<const int4*>((const bf16*)A + (size_t)(m0 + row) * K + k0 + u * 8);
        *reinterpret_cast<int4*>(&As[row * 72 + u * 8]) = av;
      }
      int4 bv = *reinterpret_cast<const int4*>(BT + (size_t)(n0 + row) * K + k0 + u * 8);
      *reinterpret_cast<int4*>(&Bs[row * 72 + u * 8]) = bv;
    }
    __syncthreads();
#pragma unroll
    for (int ks = 0; ks < 2; ++ks) {
      bf16x8 af[4], bfr[4];
#pragma unroll
      for (int mi = 0; mi < 4; ++mi)
        af[mi] = *reinterpret_cast<const bf16x8*>(
            &As[(wr * 64 + mi * 16 + lm) * 72 + ks * 32 + lqd * 8]);
#pragma unroll
      for (int ni = 0; ni < 4; ++ni)
        bfr[ni] = *reinterpret_cast<const bf16x8*>(
            &Bs[(wc * 64 + ni * 16 + lm) * 72 + ks * 32 + lqd * 8]);
#pragma unroll
      for (int mi = 0; mi < 4; ++mi)
#pragma unroll
        for (int ni = 0; ni < 4; ++ni)
          acc[mi][ni] = __builtin_amdgcn_mfma_f32_16x16x32_bf16(af[mi], bfr[ni],
                                                                acc[mi][ni], 0, 0, 0);
    }
    __syncthreads();
  }

#pragma unroll
  for (int mi = 0; mi < 4; ++mi) {
    int mbase = m0 + wr * 64 + mi * 16;
#pragma unroll
    for (int ni = 0; ni < 4; ++ni) {
      int n = n0 + wc * 64 + ni * 16 + lm;
      float bv = bias ? bias[n] : 0.0f;
      if constexpr (EPI == 3) {
        float l0 = acc[mi][ni][0] + bv, l1 = acc[mi][ni][1] + bv;
        float l2 = acc[mi][ni][2] + bv, l3 = acc[mi][ni][3] + bv;
        float mx = fmaxf(fmaxf(l0, l1), fmaxf(l2, l3));
        mx = fmaxf(mx, __shfl_xor(mx, 16, 64));
        mx = fmaxf(mx, __shfl_xor(mx, 32, 64));
        float ev[4];
        ev[0] = __expf((l0 - mx) * 0.0625f);
        ev[1] = __expf((l1 - mx) * 0.0625f);
        ev[2] = __expf((l2 - mx) * 0.0625f);
        ev[3] = __expf((l3 - mx) * 0.0625f);
        float s = ev[0] + ev[1] + ev[2] + ev[3];
        s += __shfl_xor(s, 16, 64);
        s += __shfl_xor(s, 32, 64);
        float inv = 1.0f / s;
        float rp = 0.0f;
#pragma unroll
        for (int r = 0; r < 4; ++r) {
          size_t m = (size_t)(mbase + lqd * 4 + r);
          float a = ev[r] * inv;
          C[m * 256 + n] = a;
          rp += a * b2f(e2p[m * 256 + n]);
        }
        rp += __shfl_xor(rp, 16, 64);
        rp += __shfl_xor(rp, 32, 64);
        if (lqd == 0) o1[(size_t)(mbase >> 4) * 256 + n] = f2b(rp);
      } else {
#pragma unroll
        for (int r = 0; r < 4; ++r) {
          size_t m = (size_t)(mbase + lqd * 4 + r);
          float v = acc[mi][ni][r] + bv;
          if constexpr (EPI == 1) v = fmaxf(v, 0.0f);
          if constexpr (EPI == 2) {
            int g = gidx[m];
            float qv = b2f(e0p[(m >> 4) * (size_t)256 + n]);
            float kv = b2f(e1p[(size_t)g * 256 + n]);
            float vv = b2f(e2p[(size_t)g * 256 + n]);
            C[m * (size_t)N + n] = f2b(qv - kv + v);
            o1[m * (size_t)N + n] = f2b(vv + v);
          } else if constexpr (EPI == 4) {
            v += resid[m * (size_t)N + n];
            C[m * (size_t)N + n] = v;
          } else {
            C[m * (size_t)N + n] = f2b(v);
          }
        }
      }
    }
  }
}

// ---------------- launcher ----------------
extern "C" void kernel_launch(void* const* d_in, const int* in_sizes, int n_in,
                              void* d_out, int out_size, void* d_ws, size_t ws_size,
                              hipStream_t stream) {
  const float* xyz = (const float*)d_in[0];
  const float* feat = (const float*)d_in[1];
  const float* W1 = (const float*)d_in[2];
  const float* b1 = (const float*)d_in[3];
  const float* W2 = (const float*)d_in[4];
  const float* b2 = (const float*)d_in[5];
  const float* Wd1 = (const float*)d_in[6];
  const float* bd1 = (const float*)d_in[7];
  const float* Wd2 = (const float*)d_in[8];
  const float* bd2 = (const float*)d_in[9];
  const float* Wg1 = (const float*)d_in[10];
  const float* bg1 = (const float*)d_in[11];
  const float* Wg2 = (const float*)d_in[12];
  const float* bg2 = (const float*)d_in[13];
  const float* Wq = (const float*)d_in[14];
  const float* Wk = (const float*)d_in[15];
  const float* Wv = (const float*)d_in[16];

  constexpr size_t XBUF = 0;
  constexpr size_t QBUF = 8388608;
  constexpr size_t KBUF = 16777216;
  constexpr size_t VBUF = 25165824;
  constexpr size_t RESPRE = 33554432;
  constexpr size_t GIDX = 41943040;
  constexpr size_t W1T = 42991616;
  constexpr size_t W2T = 43253760;
  constexpr size_t WQT = 43515904;
  constexpr size_t WKT = 43646976;
  constexpr size_t WVT = 43778048;
  constexpr size_t WD2T = 43909120;
  constexpr size_t WG1T = 44040192;
  constexpr size_t WG2T = 44171264;
  constexpr size_t HIDDEN = 44302336;          // [262144,256] bf16
  constexpr size_t HBUF = 178520064;           // [262144,256] bf16 (knn scratch first)
  constexpr size_t VPBUF = 312737792;
  constexpr size_t WS_NEEDED = 446955520;
  if (ws_size < WS_NEEDED) return;

  char* ws = (char*)d_ws;
  bf16* xbuf = (bf16*)(ws + XBUF);
  bf16* qbuf = (bf16*)(ws + QBUF);
  bf16* kbuf = (bf16*)(ws + KBUF);
  bf16* vbuf = (bf16*)(ws + VBUF);
  bf16* respre = (bf16*)(ws + RESPRE);
  int* gidx = (int*)(ws + GIDX);
  bf16* w1t = (bf16*)(ws + W1T);
  bf16* w2t = (bf16*)(ws + W2T);
  bf16* wqt = (bf16*)(ws + WQT);
  bf16* wkt = (bf16*)(ws + WKT);
  bf16* wvt = (bf16*)(ws + WVT);
  bf16* wd2t = (bf16*)(ws + WD2T);
  bf16* wg1t = (bf16*)(ws + WG1T);
  bf16* wg2t = (bf16*)(ws + WG2T);
  bf16* hidden = (bf16*)(ws + HIDDEN);
  bf16* hbuf = (bf16*)(ws + HBUF);
  bf16* vpbuf = (bf16*)(ws + VPBUF);

  // knn scratch lives in the (not-yet-written) HBUF region
  unsigned long long* knnkeys = (unsigned long long*)(ws + HBUF);           // 32 MB
  float4* pts4 = (float4*)(ws + HBUF + 33554432);                           // 256 KB

  float* res_out = (float*)d_out;
  float* attn_out = res_out + (size_t)16384 * 512;

  transpose_k<<<512, 256, 0, stream>>>(W1, w1t, 512, 256);
  transpose_k<<<512, 256, 0, stream>>>(W2, w2t, 256, 512);
  transpose_k<<<256, 256, 0, stream>>>(Wq, wqt, 256, 256);
  transpose_k<<<256, 256, 0, stream>>>(Wk, wkt, 256, 256);
  transpose_k<<<256, 256, 0, stream>>>(Wv, wvt, 256, 256);
  transpose_k<<<256, 256, 0, stream>>>(Wd2, wd2t, 256, 256);
  transpose_k<<<256, 256, 0, stream>>>(Wg1, wg1t, 256, 256);
  transpose_k<<<256, 256, 0, stream>>>(Wg2, wg2t, 256, 256);

  pack_pts<<<64, 256, 0, stream>>>(xyz, pts4);
  knn_partial<<<1024, 256, 0, stream>>>(pts4, knnkeys);
  knn_merge<<<64, 256, 0, stream>>>(knnkeys, gidx);

  gemm_bt<0, float, bf16><<<128 * 2, 256, 0, stream>>>(
      feat, w1t, b1, xbuf, 16384, 256, 512,
      nullptr, nullptr, nullptr, nullptr, nullptr, nullptr);
  gemm_bt<0, bf16, bf16><<<128 * 2, 256, 0, stream>>>(
      xbuf, wqt, nullptr, qbuf, 16384, 256, 256,
      nullptr, nullptr, nullptr, nullptr, nullptr, nullptr);
  gemm_bt<0, bf16, bf16><<<128 * 2, 256, 0, stream>>>(
      xbuf, wkt, nullptr, kbuf, 16384, 256, 256,
      nullptr, nullptr, nullptr, nullptr, nullptr, nullptr);
  gemm_bt<0, bf16, bf16><<<128 * 2, 256, 0, stream>>>(
      xbuf, wvt, nullptr, vbuf, 16384, 256, 256,
      nullptr, nullptr, nullptr, nullptr, nullptr, nullptr);

  hidden_kernel<<<16384, 256, 0, stream>>>(xyz, gidx, Wd1, bd1, hidden);

  gemm_bt<2, bf16, bf16><<<2048 * 2, 256, 0, stream>>>(
      hidden, wd2t, bd2, hbuf, 262144, 256, 256,
      qbuf, kbuf, vbuf, gidx, vpbuf, nullptr);
  gemm_bt<1, bf16, bf16><<<2048 * 2, 256, 0, stream>>>(
      hbuf, wg1t, bg1, hidden, 262144, 256, 256,
      nullptr, nullptr, nullptr, nullptr, nullptr, nullptr);
  gemm_bt<3, bf16, float><<<2048 * 2, 256, 0, stream>>>(
      hidden, wg2t, bg2, attn_out, 262144, 256, 256,
      nullptr, nullptr, vpbuf, nullptr, respre, nullptr);
  gemm_bt<4, bf16, float><<<128 * 4, 256, 0, stream>>>(
      respre, w2t, b2, res_out, 16384, 512, 256,
      nullptr, nullptr, nullptr, nullptr, nullptr, feat);
}